// Round 13
// baseline (88.937 us; speedup 1.0000x reference)
//
#include <hip/hip_runtime.h>
#include <math.h>

#define B_N 512
#define D_N 768
#define R_N 128
#define ALPHA 2.0f
#define BETA 50.0f
#define BASE 0.5f
#define EPS_M 0.1f
#define NB 8

typedef __attribute__((ext_vector_type(4))) float f32x4;
typedef __attribute__((ext_vector_type(8))) short s16x8;

static __device__ inline unsigned short f2bf(float f) {
    union { float f; unsigned u; } v; v.f = f;
    unsigned u = v.u;
    return (unsigned short)((u + 0x7FFFu + ((u >> 16) & 1u)) >> 16);  // RNE
}

// ---------------- Kernel 1: grouped matvec t[b] = M[re_id[b]] @ x[b] --------
// grid (128, 25), XCD-locality remap (r12 proven): all 25 blocks of a relation
// run on one XCD. y'<24 = matvec tiles; y'==24 = cui1-norm stripe.
__global__ __launch_bounds__(256, 3) void k_matvec(
    const float* __restrict__ transform, const float* __restrict__ cui0,
    const int* __restrict__ re_id, float* __restrict__ t_out,
    const float* __restrict__ cui1, unsigned short* __restrict__ cn,
    int* __restrict__ scnt) {
    int tid = threadIdx.x;
    int lane = tid & 63;
    int w = tid >> 6;
    if (blockIdx.x == 0 && blockIdx.y == 0 && tid == 0) *scnt = 0;

    // ---- XCD-locality remap (bijective: 3200 = 8 xcd * 16 r * 25 y) ----
    int linear = blockIdx.y * 128 + blockIdx.x;
    int xcd = linear & 7;
    int idx = linear >> 3;       // 0..399 within this XCD
    int rloc = idx / 25;         // 0..15
    int ytile = idx - rloc * 25; // 0..24
    int r = xcd * 16 + rloc;     // relation (also stripe id when ytile==24)

    if (ytile == 24) {  // ---- cui1 norm stripe: 4 rows per block ----
        int gw = r * 4 + w;
        const float4* s4 = (const float4*)(cui1 + (size_t)gw * D_N);
        float4 v[3];
        float ss = 0.f;
#pragma unroll
        for (int c = 0; c < 3; ++c) {
            v[c] = s4[c * 64 + lane];
            ss += v[c].x * v[c].x + v[c].y * v[c].y + v[c].z * v[c].z + v[c].w * v[c].w;
        }
#pragma unroll
        for (int off = 32; off > 0; off >>= 1) ss += __shfl_xor(ss, off, 64);
        float inv = 1.0f / fmaxf(sqrtf(ss), 1e-12f);
        ushort4* d4 = (ushort4*)(cn + (size_t)gw * D_N);
#pragma unroll
        for (int c = 0; c < 3; ++c) {
            ushort4 o;
            o.x = f2bf(v[c].x * inv); o.y = f2bf(v[c].y * inv);
            o.z = f2bf(v[c].z * inv); o.w = f2bf(v[c].w * inv);
            d4[c * 64 + lane] = o;
        }
        return;
    }

    int tile = ytile * 32;
    int g = lane >> 4;    // which of 4 rows in a unit
    int l16 = lane & 15;  // k-slot within the row

    const float* Mbase = transform + (size_t)r * ((size_t)D_N * D_N);
    int i0 = tile + w * 8 + g;
    int i1 = i0 + 4;
    const float4* M0 = (const float4*)(Mbase + (size_t)i0 * D_N);
    const float4* M1 = (const float4*)(Mbase + (size_t)i1 * D_N);
    float4 m0[12], m1[12];
#pragma unroll
    for (int c = 0; c < 12; ++c) m0[c] = M0[l16 + 16 * c];
#pragma unroll
    for (int c = 0; c < 12; ++c) m1[c] = M1[l16 + 16 * c];

    __shared__ int mem_s[B_N];
    __shared__ int cnt_s;
    __shared__ float xs[NB][D_N];  // 24 KiB

    if (tid == 0) cnt_s = 0;
    __syncthreads();
    {
        int a = re_id[tid], b = re_id[tid + 256];
        if (a == r) { int k = atomicAdd(&cnt_s, 1); mem_s[k] = tid; }
        if (b == r) { int k = atomicAdd(&cnt_s, 1); mem_s[k] = tid + 256; }
    }
    __syncthreads();
    int n = cnt_s;
    if (n == 0) return;

    for (int cs = 0; cs < n; cs += NB) {
        int nc = min(NB, n - cs);
        __syncthreads();  // previous chunk done before overwrite
        for (int idx2 = tid; idx2 < nc * 192; idx2 += 256) {
            int cb = idx2 / 192, pos = idx2 - cb * 192;
            int b = mem_s[cs + cb];
            ((float4*)xs[cb])[pos] = ((const float4*)(cui0 + (size_t)b * D_N))[pos];
        }
        __syncthreads();

        for (int cb = 0; cb < nc; ++cb) {
            const float4* xr = (const float4*)xs[cb];
            float a0 = 0.f, a1 = 0.f;
#pragma unroll
            for (int c = 0; c < 12; ++c) {
                float4 x = xr[l16 + 16 * c];
                a0 += m0[c].x * x.x + m0[c].y * x.y + m0[c].z * x.z + m0[c].w * x.w;
                a1 += m1[c].x * x.x + m1[c].y * x.y + m1[c].z * x.z + m1[c].w * x.w;
            }
            a0 += __shfl_xor(a0, 8, 64);
            a1 += __shfl_xor(a1, 8, 64);
            a0 += __shfl_xor(a0, 4, 64);
            a1 += __shfl_xor(a1, 4, 64);
            a0 += __shfl_xor(a0, 2, 64);
            a1 += __shfl_xor(a1, 2, 64);
            a0 += __shfl_xor(a0, 1, 64);
            a1 += __shfl_xor(a1, 1, 64);
            if (l16 == 0) {
                size_t ob = (size_t)mem_s[cs + cb] * D_N;
                t_out[ob + i0] = a0;
                t_out[ob + i1] = a1;
            }
        }
    }
}

// ---------------- Kernel 2: fused t-norm + gemm + loss + mean --------------
// grid 32 blocks x 512 threads (8 waves). Block b owns t-rows [16b,16b+16):
// A) normalize those rows -> bf16 LDS As[16][776] (pad: 2-way banks, free)
// B) 16x512 cosine tile: wave w owns col-tiles w*4..w*4+3; A-frag shared
//    across the 4 tiles (1 ds_read_b128 + 4 global B-frags per k-step);
//    result into LDS mat_s[16][522] (pad: 2-way banks)
// C) wave-per-row miner + MS loss from LDS (butterfly-only reductions);
//    last of 32 blocks reduces the mean.
__global__ __launch_bounds__(512) void k_fused(
    const float* __restrict__ t_in, const unsigned short* __restrict__ cn,
    const int* __restrict__ lab, float* __restrict__ row_loss,
    int* __restrict__ scnt, float* __restrict__ out) {
    __shared__ unsigned short As[16][776];
    __shared__ float mat_s[16][522];
    __shared__ int lab_s[B_N];
    __shared__ float tmp[8];
    __shared__ int is_last;

    const int tid = threadIdx.x;
    const int lane = tid & 63, w = tid >> 6;
    const int rb = blockIdx.x * 16;

    lab_s[tid] = lab[tid];

    // ---- Phase A: per-row norm + bf16 convert (wave per row, 2 rounds) ----
    for (int rr = w; rr < 16; rr += 8) {
        const float4* s4 = (const float4*)(t_in + (size_t)(rb + rr) * D_N);
        float4 v[3];
        float ss = 0.f;
#pragma unroll
        for (int c = 0; c < 3; ++c) {
            v[c] = s4[c * 64 + lane];
            ss += v[c].x * v[c].x + v[c].y * v[c].y + v[c].z * v[c].z + v[c].w * v[c].w;
        }
#pragma unroll
        for (int off = 32; off > 0; off >>= 1) ss += __shfl_xor(ss, off, 64);
        float inv = 1.0f / fmaxf(sqrtf(ss), 1e-12f);
#pragma unroll
        for (int c = 0; c < 3; ++c) {
            ushort4 o;
            o.x = f2bf(v[c].x * inv); o.y = f2bf(v[c].y * inv);
            o.z = f2bf(v[c].z * inv); o.w = f2bf(v[c].w * inv);
            *(ushort4*)&As[rr][c * 256 + lane * 4] = o;
        }
    }
    __syncthreads();

    // ---- Phase B: MFMA gemm 16 rows x 512 cols ----
    {
        const int l15 = lane & 15, lh = lane >> 4;
        f32x4 acc0 = {0.f, 0.f, 0.f, 0.f};
        f32x4 acc1 = {0.f, 0.f, 0.f, 0.f};
        f32x4 acc2 = {0.f, 0.f, 0.f, 0.f};
        f32x4 acc3 = {0.f, 0.f, 0.f, 0.f};
        const s16x8* bp0 = (const s16x8*)(cn + (size_t)((w * 4 + 0) * 16 + l15) * D_N);
        const s16x8* bp1 = (const s16x8*)(cn + (size_t)((w * 4 + 1) * 16 + l15) * D_N);
        const s16x8* bp2 = (const s16x8*)(cn + (size_t)((w * 4 + 2) * 16 + l15) * D_N);
        const s16x8* bp3 = (const s16x8*)(cn + (size_t)((w * 4 + 3) * 16 + l15) * D_N);
#pragma unroll 4
        for (int ks = 0; ks < 24; ++ks) {
            s16x8 a = *(const s16x8*)&As[l15][ks * 32 + lh * 8];
            s16x8 b0 = bp0[ks * 4 + lh];
            s16x8 b1 = bp1[ks * 4 + lh];
            s16x8 b2 = bp2[ks * 4 + lh];
            s16x8 b3 = bp3[ks * 4 + lh];
            acc0 = __builtin_amdgcn_mfma_f32_16x16x32_bf16(a, b0, acc0, 0, 0, 0);
            acc1 = __builtin_amdgcn_mfma_f32_16x16x32_bf16(a, b1, acc1, 0, 0, 0);
            acc2 = __builtin_amdgcn_mfma_f32_16x16x32_bf16(a, b2, acc2, 0, 0, 0);
            acc3 = __builtin_amdgcn_mfma_f32_16x16x32_bf16(a, b3, acc3, 0, 0, 0);
        }
        // C/D layout: col=lane&15, row=(lane>>4)*4+reg  [m89; HW-verified]
#pragma unroll
        for (int p = 0; p < 4; ++p) {
            mat_s[lh * 4 + p][(w * 4 + 0) * 16 + l15] = acc0[p];
            mat_s[lh * 4 + p][(w * 4 + 1) * 16 + l15] = acc1[p];
            mat_s[lh * 4 + p][(w * 4 + 2) * 16 + l15] = acc2[p];
            mat_s[lh * 4 + p][(w * 4 + 3) * 16 + l15] = acc3[p];
        }
    }
    __syncthreads();

    // ---- Phase C: miner + MS loss, wave per row (2 rounds) ----
    for (int rr = w; rr < 16; rr += 8) {
        int gr = rb + rr;
        int lr = lab_s[gr];
        float vv[8];
        bool mm[8];
        float mx = -INFINITY, mn = INFINITY;
#pragma unroll
        for (int c = 0; c < 8; ++c) {
            int col = lane + 64 * c;
            float v = mat_s[rr][col];
            bool m = (lab_s[col] == lr);
            vv[c] = v; mm[c] = m;
            if (m) mn = fminf(mn, v); else mx = fmaxf(mx, v);
        }
#pragma unroll
        for (int off = 32; off > 0; off >>= 1) {
            mx = fmaxf(mx, __shfl_xor(mx, off, 64));
            mn = fminf(mn, __shfl_xor(mn, off, 64));
        }
        float psum = 0.f, nsum = 0.f;
#pragma unroll
        for (int c = 0; c < 8; ++c) {
            if (mm[c] && (vv[c] - EPS_M < mx)) psum += expf(ALPHA * (BASE - vv[c]));
            if (!mm[c] && (vv[c] + EPS_M > mn)) nsum += expf(BETA * (vv[c] - BASE));
        }
#pragma unroll
        for (int off = 32; off > 0; off >>= 1) {
            psum += __shfl_xor(psum, off, 64);
            nsum += __shfl_xor(nsum, off, 64);
        }
        if (lane == 0)
            row_loss[gr] = (1.0f / ALPHA) * log1pf(psum) + (1.0f / BETA) * log1pf(nsum);
    }

    // ---- mean (last of 32 blocks) ----
    __syncthreads();
    if (tid == 0) {
        __threadfence();
        int prev = atomicAdd(scnt, 1);
        is_last = (prev == 31) ? 1 : 0;
    }
    __syncthreads();
    if (is_last) {
        __threadfence();
        float v = row_loss[tid];
#pragma unroll
        for (int off = 32; off > 0; off >>= 1) v += __shfl_xor(v, off, 64);
        if (lane == 0) tmp[w] = v;
        __syncthreads();
        if (tid == 0) {
            float s = 0.f;
#pragma unroll
            for (int i = 0; i < 8; ++i) s += tmp[i];
            out[0] = s / (float)B_N;
        }
    }
}

extern "C" void kernel_launch(void* const* d_in, const int* in_sizes, int n_in,
                              void* d_out, int out_size, void* d_ws, size_t ws_size,
                              hipStream_t stream) {
    const float* cui0      = (const float*)d_in[0];
    const float* cui1      = (const float*)d_in[1];
    const int*   re_id     = (const int*)d_in[2];
    const int*   lab1      = (const int*)d_in[4];
    const float* transform = (const float*)d_in[5];
    float* out = (float*)d_out;

    char* wsb = (char*)d_ws;
    unsigned short* cn = (unsigned short*)wsb;              // 512*768 bf16 (normalized cui1)
    float* t        = (float*)(wsb + 786432);               // 512*768 f32
    float* row_loss = (float*)(wsb + 786432 + 1572864);     // 512 f32
    int*   scnt     = (int*)(wsb + 786432 + 1572864 + 2048);// 1

    hipLaunchKernelGGL(k_matvec, dim3(R_N, 25), dim3(256), 0, stream,
                       transform, cui0, re_id, t, cui1, cn, scnt);
    hipLaunchKernelGGL(k_fused, dim3(32), dim3(512), 0, stream,
                       t, cn, lab1, row_loss, scnt, out);
}